// Round 4
// baseline (1335.786 us; speedup 1.0000x reference)
//
#include <hip/hip_runtime.h>

#define NUM_USERS 100000
#define NUM_ITEMS 50000
#define NNODES    150000
#define EMB       64
#define NEDGES    4800000
#define BATCH     4096
#define BUCKETS   586           // ceil(NNODES/256) row-buckets
#define EPB       8192          // edges per binA block
#define NBLK_A    586           // ceil(NEDGES/EPB)
#define CAP       9216          // per-bucket tmp capacity (mean 8192, sd ~90)

// l0 init: concat(user_emb, item_emb), float4 vectorized.
__global__ void init_kernel(const float* __restrict__ user_emb,
                            const float* __restrict__ item_emb,
                            float* __restrict__ cur) {
    long i = (long)blockIdx.x * blockDim.x + threadIdx.x;   // float4 units
    const long n4 = (long)NNODES * EMB / 4;
    if (i >= n4) return;
    const long nu4 = (long)NUM_USERS * EMB / 4;
    float4 v = (i < nu4) ? ((const float4*)user_emb)[i]
                         : ((const float4*)item_emb)[i - nu4];
    ((float4*)cur)[i] = v;
}

// --- CSR build ---------------------------------------------------------
// Pass A: block-local LDS binning by bucket=row>>8, then burst-contiguous
// chunk copies to tmp with ONE global atomic per (block,bucket).
// pack.x = (rowLocal<<18) | col   (col < 2^18, rowLocal < 256)
__global__ void __launch_bounds__(512) binA_lds(const int* __restrict__ rows,
                                                const int* __restrict__ cols,
                                                const float* __restrict__ vals,
                                                int* __restrict__ bfill,
                                                int2* __restrict__ tmp) {
    __shared__ int2 ebuf[EPB];                 // 64 KB bucket-sorted edges
    __shared__ int  hist[640];
    __shared__ int  startArr[640];
    __shared__ int  cursor[640];
    const int tid = threadIdx.x;

    for (int i = tid; i < 640; i += 512) hist[i] = 0;
    __syncthreads();

    // load 16 edges/thread into registers, build LDS bucket histogram
    const long base = (long)blockIdx.x * EPB;
    int  myb[16];
    int2 mye[16];
    #pragma unroll
    for (int k = 0; k < 16; ++k) {
        long e = base + (long)k * 512 + tid;
        int b = -1; int2 pk = make_int2(0, 0);
        if (e < NEDGES) {
            int r = rows[e];
            b = r >> 8;
            pk = make_int2(((r & 255) << 18) | cols[e], __float_as_int(vals[e]));
            atomicAdd(&hist[b], 1);
        }
        myb[k] = b; mye[k] = pk;
    }
    __syncthreads();

    // exclusive scan hist -> startArr/cursor (wave 0, 64-chunks with carry)
    if (tid < 64) {
        int carry = 0;
        for (int cb = 0; cb < BUCKETS; cb += 64) {
            int i = cb + tid;
            int orig = (i < BUCKETS) ? hist[i] : 0;
            int x = orig;
            #pragma unroll
            for (int d = 1; d < 64; d <<= 1) {
                int t = __shfl_up(x, d, 64);
                if (tid >= d) x += t;
            }
            int total = __shfl(x, 63, 64);
            if (i < BUCKETS) { startArr[i] = x - orig + carry; cursor[i] = x - orig + carry; }
            carry += total;
        }
    }
    __syncthreads();

    // scatter registers -> bucket-sorted LDS
    #pragma unroll
    for (int k = 0; k < 16; ++k) {
        if (myb[k] >= 0) {
            int p = atomicAdd(&cursor[myb[k]], 1);
            ebuf[p] = mye[k];
        }
    }
    __syncthreads();

    // burst-copy each bucket chunk: 1 global atomic reservation per chunk
    const int wv = tid >> 6, lane = tid & 63;
    for (int b = wv; b < BUCKETS; b += 8) {
        int cnt = hist[b];
        if (cnt == 0) continue;
        int gbase;
        if (lane == 0) gbase = atomicAdd(&bfill[b], cnt);
        gbase = __shfl(gbase, 0, 64);
        int s = startArr[b];
        long dst = (long)b * CAP + gbase;
        for (int i = lane; i < cnt; i += 64) tmp[dst + i] = ebuf[s + i];
    }
}

// exclusive scan of 586 bucket totals -> bucketBase (single wave)
__global__ void scan_buckets(const int* __restrict__ bfill, int* __restrict__ bucketBase) {
    int lane = threadIdx.x;
    int carry = 0;
    for (int cb = 0; cb < BUCKETS; cb += 64) {
        int i = cb + lane;
        int orig = (i < BUCKETS) ? bfill[i] : 0;
        int x = orig;
        #pragma unroll
        for (int d = 1; d < 64; d <<= 1) {
            int t = __shfl_up(x, d, 64);
            if (lane >= d) x += t;
        }
        int total = __shfl(x, 63, 64);
        if (i < BUCKETS) bucketBase[i] = x - orig + carry;
        carry += total;
    }
}

// Pass B: one block per bucket. LDS 256-row histogram + scan -> rowPtr,
// then scatter into the bucket's contiguous csr window (~64 KB, L2-dense).
__global__ void __launch_bounds__(256) binB_kernel(const int* __restrict__ bfill,
                                                   const int* __restrict__ bucketBase,
                                                   const int2* __restrict__ tmp,
                                                   int* __restrict__ rowPtr,
                                                   int2* __restrict__ csr) {
    const int bucket = blockIdx.x;
    __shared__ int lhist[256];
    __shared__ int rp[256];
    __shared__ int fill[256];
    const int t = threadIdx.x;
    lhist[t] = 0; fill[t] = 0;
    __syncthreads();

    const int cnt = bfill[bucket];
    const int2* src = tmp + (long)bucket * CAP;
    for (int k = t; k < cnt; k += 256)
        atomicAdd(&lhist[src[k].x >> 18], 1);
    __syncthreads();

    const int gb = bucketBase[bucket];
    if (t < 64) {
        int carry = 0;
        for (int cb = 0; cb < 256; cb += 64) {
            int i = cb + t;
            int orig = lhist[i];
            int x = orig;
            #pragma unroll
            for (int d = 1; d < 64; d <<= 1) {
                int tt = __shfl_up(x, d, 64);
                if (t >= d) x += tt;
            }
            int total = __shfl(x, 63, 64);
            rp[i] = x - orig + carry + gb;     // global exclusive offset
            carry += total;
        }
    }
    __syncthreads();

    int rowIdx = (bucket << 8) + t;            // covers rowPtr[NNODES] at bucket 585
    rowPtr[rowIdx < 150016 ? rowIdx : 150015] = rp[t];

    for (int k = t; k < cnt; k += 256) {
        int2 p = src[k];
        int rL = p.x >> 18;
        int pos = rp[rL] + atomicAdd(&fill[rL], 1);
        csr[pos] = make_int2(p.x & 0x3FFFF, p.y);
    }
}

// --- SpMM: one 16-lane quarter-wave per row, float4 slice per lane ------
__global__ void spmm_csr(const int* __restrict__ rowPtr, const int2* __restrict__ csr,
                         const float* __restrict__ cur, float* __restrict__ nxt) {
    int gtid = blockIdx.x * blockDim.x + threadIdx.x;
    int row = gtid >> 4;
    int t   = gtid & 15;
    if (row >= NNODES) return;
    int beg = rowPtr[row], end = rowPtr[row + 1];
    float4 s = make_float4(0.f, 0.f, 0.f, 0.f);
    int e = beg;
    for (; e + 3 < end; e += 4) {
        int2 p0 = csr[e];
        int2 p1 = csr[e + 1];
        int2 p2 = csr[e + 2];
        int2 p3 = csr[e + 3];
        float4 x0 = ((const float4*)(cur + (long)p0.x * EMB))[t];
        float4 x1 = ((const float4*)(cur + (long)p1.x * EMB))[t];
        float4 x2 = ((const float4*)(cur + (long)p2.x * EMB))[t];
        float4 x3 = ((const float4*)(cur + (long)p3.x * EMB))[t];
        float v0 = __int_as_float(p0.y), v1 = __int_as_float(p1.y);
        float v2 = __int_as_float(p2.y), v3 = __int_as_float(p3.y);
        s.x += v0 * x0.x; s.y += v0 * x0.y; s.z += v0 * x0.z; s.w += v0 * x0.w;
        s.x += v1 * x1.x; s.y += v1 * x1.y; s.z += v1 * x1.z; s.w += v1 * x1.w;
        s.x += v2 * x2.x; s.y += v2 * x2.y; s.z += v2 * x2.z; s.w += v2 * x2.w;
        s.x += v3 * x3.x; s.y += v3 * x3.y; s.z += v3 * x3.z; s.w += v3 * x3.w;
    }
    for (; e < end; ++e) {
        int2 p = csr[e];
        float v = __int_as_float(p.y);
        float4 x = ((const float4*)(cur + (long)p.x * EMB))[t];
        s.x += v * x.x; s.y += v * x.y; s.z += v * x.z; s.w += v * x.w;
    }
    ((float4*)nxt)[(long)row * (EMB / 4) + t] = s;
}

// One wave per batch element; lane = embedding dim.
// final = (emb + l1 + l2 + l3)/4  -> dot scaled by 1/16.
__global__ void score_kernel(const int* __restrict__ users,
                             const int* __restrict__ pos_items,
                             const int* __restrict__ neg_items,
                             const float* __restrict__ uemb,
                             const float* __restrict__ iemb,
                             const float* __restrict__ l1,
                             const float* __restrict__ l2,
                             const float* __restrict__ l3,
                             float* __restrict__ out) {
    int gtid = blockIdx.x * blockDim.x + threadIdx.x;
    int wave = gtid >> 6;
    int lane = threadIdx.x & 63;
    if (wave >= BATCH) return;
    int u = users[wave];
    int p = pos_items[wave];
    int n = neg_items[wave];
    long U = (long)u * EMB + lane;
    long P = (long)(p + NUM_USERS) * EMB + lane;
    long N = (long)(n + NUM_USERS) * EMB + lane;
    float ue = uemb[(long)u * EMB + lane] + l1[U] + l2[U] + l3[U];
    float pe = iemb[(long)p * EMB + lane] + l1[P] + l2[P] + l3[P];
    float ne = iemb[(long)n * EMB + lane] + l1[N] + l2[N] + l3[N];
    float ps = ue * pe;
    float ns = ue * ne;
    #pragma unroll
    for (int off = 32; off > 0; off >>= 1) {
        ps += __shfl_down(ps, off, 64);
        ns += __shfl_down(ns, off, 64);
    }
    if (lane == 0) {
        out[wave]         = ps * 0.0625f;
        out[BATCH + wave] = ns * 0.0625f;
    }
}

extern "C" void kernel_launch(void* const* d_in, const int* in_sizes, int n_in,
                              void* d_out, int out_size, void* d_ws, size_t ws_size,
                              hipStream_t stream) {
    const int*   users = (const int*)d_in[0];
    const int*   pos   = (const int*)d_in[1];
    const int*   neg   = (const int*)d_in[2];
    const int*   rows  = (const int*)d_in[3];
    const int*   cols  = (const int*)d_in[4];
    const float* vals  = (const float*)d_in[5];
    const float* uemb  = (const float*)d_in[6];
    const float* iemb  = (const float*)d_in[7];
    float* out = (float*)d_out;

    const size_t bufElems = (size_t)NNODES * EMB;       // 9.6M floats = 38.4 MB
    float* bufA    = (float*)d_ws;                      // l0 (emb), later l3
    float* bufB    = bufA + bufElems;                   // l1
    float* bufC    = bufB + bufElems;                   // l2
    int2*  csr     = (int2*)(bufC + bufElems);          // NEDGES int2
    int*   rowPtr  = (int*)(csr + NEDGES);              // 150016 ints
    int*   bfill   = rowPtr + 150016;                   // 640
    int*   bucketB = bfill + 640;                       // 640
    int2*  tmp     = (int2*)bufB;                       // 586*9216*8 = 43.2 MB
                                                        // aliases bufB+bufC; consumed
                                                        // by binB before spmm writes

    hipMemsetAsync(bfill, 0, 640 * sizeof(int), stream);

    // CSR build: LDS-binned append -> bucket scan -> per-bucket resolve
    binA_lds<<<NBLK_A, 512, 0, stream>>>(rows, cols, vals, bfill, tmp);
    scan_buckets<<<1, 64, 0, stream>>>(bfill, bucketB);
    binB_kernel<<<BUCKETS, 256, 0, stream>>>(bfill, bucketB, tmp, rowPtr, csr);

    // init l0
    const long n4 = (long)bufElems / 4;
    init_kernel<<<(int)((n4 + 255) / 256), 256, 0, stream>>>(uemb, iemb, bufA);

    // 3 propagation layers: l1=A·l0, l2=A·l1, l3=A·l2 (l3 overwrites l0)
    const long nth = (long)NNODES * 16;
    const int  spmmGrid = (int)((nth + 255) / 256);
    spmm_csr<<<spmmGrid, 256, 0, stream>>>(rowPtr, csr, bufA, bufB);
    spmm_csr<<<spmmGrid, 256, 0, stream>>>(rowPtr, csr, bufB, bufC);
    spmm_csr<<<spmmGrid, 256, 0, stream>>>(rowPtr, csr, bufC, bufA);

    score_kernel<<<(BATCH * 64) / 256, 256, 0, stream>>>(users, pos, neg,
                                                         uemb, iemb, bufB, bufC, bufA, out);
}

// Round 5
// 569.325 us; speedup vs baseline: 2.3463x; 2.3463x over previous
//
#include <hip/hip_runtime.h>

#define NUM_USERS 100000
#define NUM_ITEMS 50000
#define NNODES    150000
#define EMB       64
#define NEDGES    4800000
#define BATCH     4096
#define BUCKETS   586           // ceil(NNODES/256) row-buckets
#define EPB       8192          // edges per binA block
#define NBLK_A    586           // ceil(NEDGES/EPB)
#define CAP       9216          // per-bucket tmp capacity (mean 8191, +11 sigma)

typedef unsigned short u16;
typedef unsigned int   u32;

__device__ inline float bf2f(u16 u) { return __uint_as_float(((u32)u) << 16); }
__device__ inline u16 f2bf(float f) {                 // RNE
    u32 b = __float_as_uint(f);
    b += 0x7FFFu + ((b >> 16) & 1u);
    return (u16)(b >> 16);
}
__device__ inline u32 pack2(float a, float b) {
    return (u32)f2bf(a) | ((u32)f2bf(b) << 16);
}

// l0 init: concat(user_emb, item_emb) -> bf16 table.
__global__ void init_kernel(const float* __restrict__ user_emb,
                            const float* __restrict__ item_emb,
                            u16* __restrict__ l0) {
    long i = (long)blockIdx.x * blockDim.x + threadIdx.x;   // float4 units
    const long n4 = (long)NNODES * EMB / 4;
    if (i >= n4) return;
    const long nu4 = (long)NUM_USERS * EMB / 4;
    float4 v = (i < nu4) ? ((const float4*)user_emb)[i]
                         : ((const float4*)item_emb)[i - nu4];
    ushort4 o;
    o.x = f2bf(v.x); o.y = f2bf(v.y); o.z = f2bf(v.z); o.w = f2bf(v.w);
    ((ushort4*)l0)[i] = o;
}

// --- CSR build ---------------------------------------------------------
// Pass A v2: LDS histogram -> parallel per-bucket global reservation ->
// direct scatter to bucket-chunked tmp. No edge staging, no spills.
// pack.x = (rowLocal<<18) | col   (col < 2^18, rowLocal < 256)
__global__ void __launch_bounds__(512) binA_kernel(const int* __restrict__ rows,
                                                   const int* __restrict__ cols,
                                                   const float* __restrict__ vals,
                                                   int* __restrict__ bfill,
                                                   int2* __restrict__ tmp) {
    __shared__ int hist[640];
    __shared__ int cursor[640];
    const int tid = threadIdx.x;
    for (int i = tid; i < 640; i += 512) hist[i] = 0;
    __syncthreads();

    const long base = (long)blockIdx.x * EPB;
    #pragma unroll
    for (int k = 0; k < 16; ++k) {
        long e = base + (long)k * 512 + tid;
        if (e < NEDGES) atomicAdd(&hist[rows[e] >> 8], 1);
    }
    __syncthreads();

    // one global atomic per non-empty (block,bucket), all threads in parallel
    for (int b = tid; b < BUCKETS; b += 512) {
        int h = hist[b];
        cursor[b] = h ? b * CAP + atomicAdd(&bfill[b], h) : 0;
    }
    __syncthreads();

    #pragma unroll
    for (int k = 0; k < 16; ++k) {
        long e = base + (long)k * 512 + tid;
        if (e < NEDGES) {
            int r = rows[e];
            int pos = atomicAdd(&cursor[r >> 8], 1);
            tmp[pos] = make_int2(((r & 255) << 18) | cols[e], __float_as_int(vals[e]));
        }
    }
}

// exclusive scan of 586 bucket totals -> bucketBase (single wave)
__global__ void scan_buckets(const int* __restrict__ bfill, int* __restrict__ bucketBase) {
    int lane = threadIdx.x;
    int carry = 0;
    for (int cb = 0; cb < BUCKETS; cb += 64) {
        int i = cb + lane;
        int orig = (i < BUCKETS) ? bfill[i] : 0;
        int x = orig;
        #pragma unroll
        for (int d = 1; d < 64; d <<= 1) {
            int t = __shfl_up(x, d, 64);
            if (lane >= d) x += t;
        }
        int total = __shfl(x, 63, 64);
        if (i < BUCKETS) bucketBase[i] = x - orig + carry;
        carry += total;
    }
}

// Pass B: one block per bucket. LDS 256-row histogram + scan -> rowPtr,
// then scatter into the bucket's contiguous csr window (~64 KB, L2-dense).
__global__ void __launch_bounds__(256) binB_kernel(const int* __restrict__ bfill,
                                                   const int* __restrict__ bucketBase,
                                                   const int2* __restrict__ tmp,
                                                   int* __restrict__ rowPtr,
                                                   int2* __restrict__ csr) {
    const int bucket = blockIdx.x;
    __shared__ int lhist[256];
    __shared__ int rp[256];
    __shared__ int fill[256];
    const int t = threadIdx.x;
    lhist[t] = 0; fill[t] = 0;
    __syncthreads();

    const int cnt = bfill[bucket];
    const int2* src = tmp + (long)bucket * CAP;
    for (int k = t; k < cnt; k += 256)
        atomicAdd(&lhist[src[k].x >> 18], 1);
    __syncthreads();

    const int gb = bucketBase[bucket];
    if (t < 64) {
        int carry = 0;
        for (int cb = 0; cb < 256; cb += 64) {
            int i = cb + t;
            int orig = lhist[i];
            int x = orig;
            #pragma unroll
            for (int d = 1; d < 64; d <<= 1) {
                int tt = __shfl_up(x, d, 64);
                if (t >= d) x += tt;
            }
            int total = __shfl(x, 63, 64);
            rp[i] = x - orig + carry + gb;     // global exclusive offset
            carry += total;
        }
    }
    __syncthreads();

    int rowIdx = (bucket << 8) + t;            // max 150015; covers rowPtr[150000]
    rowPtr[rowIdx] = rp[t];

    for (int k = t; k < cnt; k += 256) {
        int2 p = src[k];
        int rL = p.x >> 18;
        int pos = rp[rL] + atomicAdd(&fill[rL], 1);
        csr[pos] = make_int2(p.x & 0x3FFFF, p.y);
    }
}

// --- SpMM: 8 lanes per row, each lane owns 8 bf16 dims (one uint4 gather) --
__global__ void spmm_csr(const int* __restrict__ rowPtr, const int2* __restrict__ csr,
                         const u16* __restrict__ cur, u16* __restrict__ nxt) {
    int gtid = blockIdx.x * blockDim.x + threadIdx.x;
    int row = gtid >> 3;
    int t   = gtid & 7;
    if (row >= NNODES) return;
    int beg = rowPtr[row], end = rowPtr[row + 1];
    float a[8];
    #pragma unroll
    for (int i = 0; i < 8; ++i) a[i] = 0.f;

    #define ACC(P) { \
        float v = __int_as_float((P).y); \
        uint4 x = *(const uint4*)(cur + ((long)(P).x << 6) + (t << 3)); \
        a[0] += v * __uint_as_float(x.x << 16); \
        a[1] += v * __uint_as_float(x.x & 0xFFFF0000u); \
        a[2] += v * __uint_as_float(x.y << 16); \
        a[3] += v * __uint_as_float(x.y & 0xFFFF0000u); \
        a[4] += v * __uint_as_float(x.z << 16); \
        a[5] += v * __uint_as_float(x.z & 0xFFFF0000u); \
        a[6] += v * __uint_as_float(x.w << 16); \
        a[7] += v * __uint_as_float(x.w & 0xFFFF0000u); }

    int e = beg;
    for (; e + 3 < end; e += 4) {
        int2 p0 = csr[e];
        int2 p1 = csr[e + 1];
        int2 p2 = csr[e + 2];
        int2 p3 = csr[e + 3];
        ACC(p0); ACC(p1); ACC(p2); ACC(p3);
    }
    for (; e < end; ++e) {
        int2 p = csr[e];
        ACC(p);
    }
    #undef ACC

    uint4 o;
    o.x = pack2(a[0], a[1]);
    o.y = pack2(a[2], a[3]);
    o.z = pack2(a[4], a[5]);
    o.w = pack2(a[6], a[7]);
    *(uint4*)(nxt + ((long)row << 6) + (t << 3)) = o;
}

// One wave per batch element; lane = embedding dim.
// final = (emb + l1 + l2 + l3)/4  -> dot scaled by 1/16.
__global__ void score_kernel(const int* __restrict__ users,
                             const int* __restrict__ pos_items,
                             const int* __restrict__ neg_items,
                             const float* __restrict__ uemb,
                             const float* __restrict__ iemb,
                             const u16* __restrict__ l1,
                             const u16* __restrict__ l2,
                             const u16* __restrict__ l3,
                             float* __restrict__ out) {
    int gtid = blockIdx.x * blockDim.x + threadIdx.x;
    int wave = gtid >> 6;
    int lane = threadIdx.x & 63;
    if (wave >= BATCH) return;
    int u = users[wave];
    int p = pos_items[wave];
    int n = neg_items[wave];
    long U = (long)u * EMB + lane;
    long P = (long)(p + NUM_USERS) * EMB + lane;
    long N = (long)(n + NUM_USERS) * EMB + lane;
    float ue = uemb[(long)u * EMB + lane] + bf2f(l1[U]) + bf2f(l2[U]) + bf2f(l3[U]);
    float pe = iemb[(long)p * EMB + lane] + bf2f(l1[P]) + bf2f(l2[P]) + bf2f(l3[P]);
    float ne = iemb[(long)n * EMB + lane] + bf2f(l1[N]) + bf2f(l2[N]) + bf2f(l3[N]);
    float ps = ue * pe;
    float ns = ue * ne;
    #pragma unroll
    for (int off = 32; off > 0; off >>= 1) {
        ps += __shfl_down(ps, off, 64);
        ns += __shfl_down(ns, off, 64);
    }
    if (lane == 0) {
        out[wave]         = ps * 0.0625f;
        out[BATCH + wave] = ns * 0.0625f;
    }
}

extern "C" void kernel_launch(void* const* d_in, const int* in_sizes, int n_in,
                              void* d_out, int out_size, void* d_ws, size_t ws_size,
                              hipStream_t stream) {
    const int*   users = (const int*)d_in[0];
    const int*   pos   = (const int*)d_in[1];
    const int*   neg   = (const int*)d_in[2];
    const int*   rows  = (const int*)d_in[3];
    const int*   cols  = (const int*)d_in[4];
    const float* vals  = (const float*)d_in[5];
    const float* uemb  = (const float*)d_in[6];
    const float* iemb  = (const float*)d_in[7];
    float* out = (float*)d_out;

    const size_t tblElems = (size_t)NNODES * EMB;       // bf16 elems, 19.2 MB each
    u16*  B0      = (u16*)d_ws;                         // l0, later l3
    u16*  B1      = B0 + tblElems;                      // l1
    u16*  B2      = B1 + tblElems;                      // l2
    int2* csr     = (int2*)(B2 + tblElems);             // NEDGES int2 = 38.4 MB
    int*  rowPtr  = (int*)(csr + NEDGES);               // 150016 ints
    int*  bfill   = rowPtr + 150016;                    // 640
    int*  bucketB = bfill + 640;                        // 640
    int2* tmp     = (int2*)B0;                          // 586*9216*8 = 43.2 MB,
                                                        // aliases B0..B2; consumed by
                                                        // binB before init writes B0

    hipMemsetAsync(bfill, 0, 640 * sizeof(int), stream);

    // CSR build: hist+reserve+scatter -> bucket scan -> per-bucket resolve
    binA_kernel<<<NBLK_A, 512, 0, stream>>>(rows, cols, vals, bfill, tmp);
    scan_buckets<<<1, 64, 0, stream>>>(bfill, bucketB);
    binB_kernel<<<BUCKETS, 256, 0, stream>>>(bfill, bucketB, tmp, rowPtr, csr);

    // init l0 (bf16)
    const long n4 = (long)tblElems / 4;
    init_kernel<<<(int)((n4 + 255) / 256), 256, 0, stream>>>(uemb, iemb, B0);

    // 3 propagation layers: l1=A·l0, l2=A·l1, l3=A·l2 (l3 overwrites l0)
    const long nth = (long)NNODES * 8;
    const int  spmmGrid = (int)((nth + 255) / 256);
    spmm_csr<<<spmmGrid, 256, 0, stream>>>(rowPtr, csr, B0, B1);
    spmm_csr<<<spmmGrid, 256, 0, stream>>>(rowPtr, csr, B1, B2);
    spmm_csr<<<spmmGrid, 256, 0, stream>>>(rowPtr, csr, B2, B0);

    score_kernel<<<(BATCH * 64) / 256, 256, 0, stream>>>(users, pos, neg,
                                                         uemb, iemb, B1, B2, B0, out);
}

// Round 6
// 556.808 us; speedup vs baseline: 2.3990x; 1.0225x over previous
//
#include <hip/hip_runtime.h>

#define NUM_USERS 100000
#define NUM_ITEMS 50000
#define NNODES    150000
#define EMB       64
#define NEDGES    4800000
#define BATCH     4096
#define BUCKETS   293           // 512-row buckets (293*512 = 150016 >= NNODES)
#define BROWS     512
#define EPB       8192          // edges per binA block
#define NBLK_A    586           // ceil(NEDGES/EPB)
#define CAP       17408         // per-bucket tmp capacity (mean 16382, +8 sigma)
#define INIT_BLKS 2344          // ceil(2.4M float4-units / 1024)

typedef unsigned short u16;
typedef unsigned int   u32;

__device__ inline float bf2f(u16 u) { return __uint_as_float(((u32)u) << 16); }
__device__ inline u16 f2bf(float f) {                 // RNE
    u32 b = __float_as_uint(f);
    b += 0x7FFFu + ((b >> 16) & 1u);
    return (u16)(b >> 16);
}
__device__ inline u32 pack2(float a, float b) {
    return (u32)f2bf(a) | ((u32)f2bf(b) << 16);
}

__device__ inline void init_body(const float* __restrict__ user_emb,
                                 const float* __restrict__ item_emb,
                                 u16* __restrict__ l0, long i) {
    const long n4 = (long)NNODES * EMB / 4;
    if (i >= n4) return;
    const long nu4 = (long)NUM_USERS * EMB / 4;
    float4 v = (i < nu4) ? ((const float4*)user_emb)[i]
                         : ((const float4*)item_emb)[i - nu4];
    ushort4 o;
    o.x = f2bf(v.x); o.y = f2bf(v.y); o.z = f2bf(v.z); o.w = f2bf(v.w);
    ((ushort4*)l0)[i] = o;
}

// standalone init (aliased-workspace path)
__global__ void init_kernel(const float* __restrict__ user_emb,
                            const float* __restrict__ item_emb,
                            u16* __restrict__ l0) {
    init_body(user_emb, item_emb, l0, (long)blockIdx.x * blockDim.x + threadIdx.x);
}

// --- CSR build ---------------------------------------------------------
// Pass A: LDS bucket histogram -> parallel per-bucket global reservation ->
// direct scatter to bucket-chunked tmp. Optional fused init blocks ride along.
// pack.x = (rowLocal<<18) | col   (col < 2^18, rowLocal < 512)
__global__ void __launch_bounds__(512) binA_kernel(const int* __restrict__ rows,
                                                   const int* __restrict__ cols,
                                                   const float* __restrict__ vals,
                                                   int* __restrict__ bfill,
                                                   int2* __restrict__ tmp,
                                                   int doInit,
                                                   const float* __restrict__ uemb,
                                                   const float* __restrict__ iemb,
                                                   u16* __restrict__ l0) {
    if (blockIdx.x >= NBLK_A) {                     // fused init blocks
        long ib = blockIdx.x - NBLK_A;
        long i = ib * 1024 + threadIdx.x;
        init_body(uemb, iemb, l0, i);
        init_body(uemb, iemb, l0, i + 512);
        return;
    }
    __shared__ int hist[BUCKETS];
    __shared__ int cursor[BUCKETS];
    const int tid = threadIdx.x;
    for (int i = tid; i < BUCKETS; i += 512) hist[i] = 0;
    __syncthreads();

    const long base = (long)blockIdx.x * EPB;
    #pragma unroll
    for (int k = 0; k < 16; ++k) {
        long e = base + (long)k * 512 + tid;
        if (e < NEDGES) atomicAdd(&hist[rows[e] >> 9], 1);
    }
    __syncthreads();

    // one global atomic per non-empty (block,bucket), all threads in parallel
    for (int b = tid; b < BUCKETS; b += 512) {
        int h = hist[b];
        cursor[b] = h ? b * CAP + atomicAdd(&bfill[b], h) : 0;
    }
    __syncthreads();

    #pragma unroll
    for (int k = 0; k < 16; ++k) {
        long e = base + (long)k * 512 + tid;
        if (e < NEDGES) {
            int r = rows[e];
            int pos = atomicAdd(&cursor[r >> 9], 1);
            tmp[pos] = make_int2(((r & 511) << 18) | cols[e], __float_as_int(vals[e]));
        }
    }
}

// exclusive scan of bucket totals -> bucketBase (single wave)
__global__ void scan_buckets(const int* __restrict__ bfill, int* __restrict__ bucketBase) {
    int lane = threadIdx.x;
    int carry = 0;
    for (int cb = 0; cb < BUCKETS; cb += 64) {
        int i = cb + lane;
        int orig = (i < BUCKETS) ? bfill[i] : 0;
        int x = orig;
        #pragma unroll
        for (int d = 1; d < 64; d <<= 1) {
            int t = __shfl_up(x, d, 64);
            if (lane >= d) x += t;
        }
        int total = __shfl(x, 63, 64);
        if (i < BUCKETS) bucketBase[i] = x - orig + carry;
        carry += total;
    }
}

// Pass B: one block per bucket. LDS 512-row histogram + scan -> rowPtr,
// then scatter into the bucket's contiguous csr window (~131 KB, L2-dense).
__global__ void __launch_bounds__(512) binB_kernel(const int* __restrict__ bfill,
                                                   const int* __restrict__ bucketBase,
                                                   const int2* __restrict__ tmp,
                                                   int* __restrict__ rowPtr,
                                                   int2* __restrict__ csr) {
    const int bucket = blockIdx.x;
    __shared__ int lhist[BROWS];
    __shared__ int rp[BROWS];
    __shared__ int fill[BROWS];
    const int t = threadIdx.x;
    lhist[t] = 0; fill[t] = 0;
    __syncthreads();

    const int cnt = bfill[bucket];
    const int2* src = tmp + (long)bucket * CAP;
    for (int k = t; k < cnt; k += 512)
        atomicAdd(&lhist[src[k].x >> 18], 1);
    __syncthreads();

    const int gb = bucketBase[bucket];
    if (t < 64) {
        int carry = 0;
        for (int cb = 0; cb < BROWS; cb += 64) {
            int i = cb + t;
            int orig = lhist[i];
            int x = orig;
            #pragma unroll
            for (int d = 1; d < 64; d <<= 1) {
                int tt = __shfl_up(x, d, 64);
                if (t >= d) x += tt;
            }
            int total = __shfl(x, 63, 64);
            rp[i] = x - orig + carry + gb;     // global exclusive offset
            carry += total;
        }
    }
    __syncthreads();

    int rowIdx = bucket * BROWS + t;           // max 150015; covers rowPtr[150000]
    rowPtr[rowIdx] = rp[t];

    for (int k = t; k < cnt; k += 512) {
        int2 p = src[k];
        int rL = p.x >> 18;
        int pos = rp[rL] + atomicAdd(&fill[rL], 1);
        csr[pos] = make_int2(p.x & 0x3FFFF, p.y);
    }
}

// --- SpMM: 8 lanes per row, each lane owns 8 bf16 dims (one uint4 gather) --
__global__ void spmm_csr(const int* __restrict__ rowPtr, const int2* __restrict__ csr,
                         const u16* __restrict__ cur, u16* __restrict__ nxt) {
    int gtid = blockIdx.x * blockDim.x + threadIdx.x;
    int row = gtid >> 3;
    int t   = gtid & 7;
    if (row >= NNODES) return;
    int beg = rowPtr[row], end = rowPtr[row + 1];
    float a[8];
    #pragma unroll
    for (int i = 0; i < 8; ++i) a[i] = 0.f;

    #define ACCX(V, X) { \
        a[0] += (V) * __uint_as_float((X).x << 16); \
        a[1] += (V) * __uint_as_float((X).x & 0xFFFF0000u); \
        a[2] += (V) * __uint_as_float((X).y << 16); \
        a[3] += (V) * __uint_as_float((X).y & 0xFFFF0000u); \
        a[4] += (V) * __uint_as_float((X).z << 16); \
        a[5] += (V) * __uint_as_float((X).z & 0xFFFF0000u); \
        a[6] += (V) * __uint_as_float((X).w << 16); \
        a[7] += (V) * __uint_as_float((X).w & 0xFFFF0000u); }

    int e = beg;
    for (; e + 7 < end; e += 8) {            // 8 outstanding gathers
        int2 p[8];
        #pragma unroll
        for (int j = 0; j < 8; ++j) p[j] = csr[e + j];
        uint4 x[8];
        #pragma unroll
        for (int j = 0; j < 8; ++j)
            x[j] = *(const uint4*)(cur + ((long)p[j].x << 6) + (t << 3));
        #pragma unroll
        for (int j = 0; j < 8; ++j) {
            float v = __int_as_float(p[j].y);
            ACCX(v, x[j]);
        }
    }
    for (; e < end; ++e) {
        int2 p = csr[e];
        float v = __int_as_float(p.y);
        uint4 x = *(const uint4*)(cur + ((long)p.x << 6) + (t << 3));
        ACCX(v, x);
    }
    #undef ACCX

    uint4 o;
    o.x = pack2(a[0], a[1]);
    o.y = pack2(a[2], a[3]);
    o.z = pack2(a[4], a[5]);
    o.w = pack2(a[6], a[7]);
    *(uint4*)(nxt + ((long)row << 6) + (t << 3)) = o;
}

// One wave per batch element; lane = embedding dim.
// final = (emb + l1 + l2 + l3)/4  -> dot scaled by 1/16.
__global__ void score_kernel(const int* __restrict__ users,
                             const int* __restrict__ pos_items,
                             const int* __restrict__ neg_items,
                             const float* __restrict__ uemb,
                             const float* __restrict__ iemb,
                             const u16* __restrict__ l1,
                             const u16* __restrict__ l2,
                             const u16* __restrict__ l3,
                             float* __restrict__ out) {
    int gtid = blockIdx.x * blockDim.x + threadIdx.x;
    int wave = gtid >> 6;
    int lane = threadIdx.x & 63;
    if (wave >= BATCH) return;
    int u = users[wave];
    int p = pos_items[wave];
    int n = neg_items[wave];
    long U = (long)u * EMB + lane;
    long P = (long)(p + NUM_USERS) * EMB + lane;
    long N = (long)(n + NUM_USERS) * EMB + lane;
    float ue = uemb[(long)u * EMB + lane] + bf2f(l1[U]) + bf2f(l2[U]) + bf2f(l3[U]);
    float pe = iemb[(long)p * EMB + lane] + bf2f(l1[P]) + bf2f(l2[P]) + bf2f(l3[P]);
    float ne = iemb[(long)n * EMB + lane] + bf2f(l1[N]) + bf2f(l2[N]) + bf2f(l3[N]);
    float ps = ue * pe;
    float ns = ue * ne;
    #pragma unroll
    for (int off = 32; off > 0; off >>= 1) {
        ps += __shfl_down(ps, off, 64);
        ns += __shfl_down(ns, off, 64);
    }
    if (lane == 0) {
        out[wave]         = ps * 0.0625f;
        out[BATCH + wave] = ns * 0.0625f;
    }
}

extern "C" void kernel_launch(void* const* d_in, const int* in_sizes, int n_in,
                              void* d_out, int out_size, void* d_ws, size_t ws_size,
                              hipStream_t stream) {
    const int*   users = (const int*)d_in[0];
    const int*   pos   = (const int*)d_in[1];
    const int*   neg   = (const int*)d_in[2];
    const int*   rows  = (const int*)d_in[3];
    const int*   cols  = (const int*)d_in[4];
    const float* vals  = (const float*)d_in[5];
    const float* uemb  = (const float*)d_in[6];
    const float* iemb  = (const float*)d_in[7];
    float* out = (float*)d_out;

    const size_t tblElems = (size_t)NNODES * EMB;       // bf16 elems, 19.2 MB each
    u16*  B0      = (u16*)d_ws;                         // l0, later l3
    u16*  B1      = B0 + tblElems;                      // l1
    u16*  B2      = B1 + tblElems;                      // l2
    int2* csr     = (int2*)(B2 + tblElems);             // NEDGES int2 = 38.4 MB
    int*  rowPtr  = (int*)(csr + NEDGES);               // 150016 ints
    int*  bfill   = rowPtr + 150016;                    // pad 320
    int*  bucketB = bfill + 320;                        // pad 320
    int*  tailEnd = bucketB + 320;

    const size_t tmpBytes = (size_t)BUCKETS * CAP * sizeof(int2);   // 40.8 MB
    const size_t baseBytes = (size_t)((char*)tailEnd - (char*)d_ws);
    const bool  bigws = ws_size >= baseBytes + tmpBytes;
    // bigws: tmp un-aliased -> init can be fused into binA's grid.
    // else : tmp aliases B0..B2 (consumed by binB before init writes B0).
    int2* tmp = bigws ? (int2*)tailEnd : (int2*)B0;

    hipMemsetAsync(bfill, 0, 320 * sizeof(int), stream);

    // CSR build: hist+reserve+scatter (+fused init) -> bucket scan -> resolve
    int gridA = NBLK_A + (bigws ? INIT_BLKS : 0);
    binA_kernel<<<gridA, 512, 0, stream>>>(rows, cols, vals, bfill, tmp,
                                           bigws ? 1 : 0, uemb, iemb, B0);
    scan_buckets<<<1, 64, 0, stream>>>(bfill, bucketB);
    binB_kernel<<<BUCKETS, 512, 0, stream>>>(bfill, bucketB, tmp, rowPtr, csr);

    if (!bigws) {
        const long n4 = (long)tblElems / 4;
        init_kernel<<<(int)((n4 + 255) / 256), 256, 0, stream>>>(uemb, iemb, B0);
    }

    // 3 propagation layers: l1=A·l0, l2=A·l1, l3=A·l2 (l3 overwrites l0)
    const long nth = (long)NNODES * 8;
    const int  spmmGrid = (int)((nth + 255) / 256);
    spmm_csr<<<spmmGrid, 256, 0, stream>>>(rowPtr, csr, B0, B1);
    spmm_csr<<<spmmGrid, 256, 0, stream>>>(rowPtr, csr, B1, B2);
    spmm_csr<<<spmmGrid, 256, 0, stream>>>(rowPtr, csr, B2, B0);

    score_kernel<<<(BATCH * 64) / 256, 256, 0, stream>>>(users, pos, neg,
                                                         uemb, iemb, B1, B2, B0, out);
}

// Round 7
// 482.390 us; speedup vs baseline: 2.7691x; 1.1543x over previous
//
#include <hip/hip_runtime.h>

#define NUM_USERS 100000
#define NUM_ITEMS 50000
#define NNODES    150000
#define EMB       64
#define NEDGES    4800000
#define BATCH     4096
#define BUCKETS   293           // 512-row buckets (293*512 = 150016 >= NNODES)
#define BROWS     512
#define EPB       8192          // edges per binA block
#define NBLK_A    586           // ceil(NEDGES/EPB)
#define CAP       17408         // per-bucket tmp capacity (mean 16382, +8 sigma)
#define INIT_BLKS 2344          // ceil(2.4M float4-units / 1024)
#define NSAMP     (3 * BATCH)   // sampled rows for layer 3

typedef unsigned short u16;
typedef unsigned int   u32;

__device__ inline float bf2f(u16 u) { return __uint_as_float(((u32)u) << 16); }
__device__ inline u16 f2bf(float f) {                 // RNE
    u32 b = __float_as_uint(f);
    b += 0x7FFFu + ((b >> 16) & 1u);
    return (u16)(b >> 16);
}
__device__ inline u32 pack2(float a, float b) {
    return (u32)f2bf(a) | ((u32)f2bf(b) << 16);
}

__device__ inline void init_body(const float* __restrict__ user_emb,
                                 const float* __restrict__ item_emb,
                                 u16* __restrict__ l0, long i) {
    const long n4 = (long)NNODES * EMB / 4;
    if (i >= n4) return;
    const long nu4 = (long)NUM_USERS * EMB / 4;
    float4 v = (i < nu4) ? ((const float4*)user_emb)[i]
                         : ((const float4*)item_emb)[i - nu4];
    ushort4 o;
    o.x = f2bf(v.x); o.y = f2bf(v.y); o.z = f2bf(v.z); o.w = f2bf(v.w);
    ((ushort4*)l0)[i] = o;
}

// standalone init (aliased-workspace path)
__global__ void init_kernel(const float* __restrict__ user_emb,
                            const float* __restrict__ item_emb,
                            u16* __restrict__ l0) {
    init_body(user_emb, item_emb, l0, (long)blockIdx.x * blockDim.x + threadIdx.x);
}

// --- CSR build ---------------------------------------------------------
// Pass A: LDS bucket histogram -> parallel per-bucket global reservation ->
// direct scatter to bucket-chunked tmp. Optional fused init blocks ride along.
// pack.x = (rowLocal<<18) | col   (col < 2^18, rowLocal < 512)
__global__ void __launch_bounds__(512) binA_kernel(const int* __restrict__ rows,
                                                   const int* __restrict__ cols,
                                                   const float* __restrict__ vals,
                                                   int* __restrict__ bfill,
                                                   int2* __restrict__ tmp,
                                                   const float* __restrict__ uemb,
                                                   const float* __restrict__ iemb,
                                                   u16* __restrict__ l0) {
    if (blockIdx.x >= NBLK_A) {                     // fused init blocks
        long ib = blockIdx.x - NBLK_A;
        long i = ib * 1024 + threadIdx.x;
        init_body(uemb, iemb, l0, i);
        init_body(uemb, iemb, l0, i + 512);
        return;
    }
    __shared__ int hist[BUCKETS];
    __shared__ int cursor[BUCKETS];
    const int tid = threadIdx.x;
    for (int i = tid; i < BUCKETS; i += 512) hist[i] = 0;
    __syncthreads();

    const long base = (long)blockIdx.x * EPB;
    #pragma unroll
    for (int k = 0; k < 16; ++k) {
        long e = base + (long)k * 512 + tid;
        if (e < NEDGES) atomicAdd(&hist[rows[e] >> 9], 1);
    }
    __syncthreads();

    // one global atomic per non-empty (block,bucket), all threads in parallel
    for (int b = tid; b < BUCKETS; b += 512) {
        int h = hist[b];
        cursor[b] = h ? b * CAP + atomicAdd(&bfill[b], h) : 0;
    }
    __syncthreads();

    #pragma unroll
    for (int k = 0; k < 16; ++k) {
        long e = base + (long)k * 512 + tid;
        if (e < NEDGES) {
            int r = rows[e];
            int pos = atomicAdd(&cursor[r >> 9], 1);
            tmp[pos] = make_int2(((r & 511) << 18) | cols[e], __float_as_int(vals[e]));
        }
    }
}

// exclusive scan of bucket totals -> bucketBase (single wave)
__global__ void scan_buckets(const int* __restrict__ bfill, int* __restrict__ bucketBase) {
    int lane = threadIdx.x;
    int carry = 0;
    for (int cb = 0; cb < BUCKETS; cb += 64) {
        int i = cb + lane;
        int orig = (i < BUCKETS) ? bfill[i] : 0;
        int x = orig;
        #pragma unroll
        for (int d = 1; d < 64; d <<= 1) {
            int t = __shfl_up(x, d, 64);
            if (lane >= d) x += t;
        }
        int total = __shfl(x, 63, 64);
        if (i < BUCKETS) bucketBase[i] = x - orig + carry;
        carry += total;
    }
}

// Pass B: one block per bucket. LDS 512-row histogram + scan -> rowPtr,
// then scatter into the bucket's contiguous csr window (~131 KB, L2-dense).
__global__ void __launch_bounds__(512) binB_kernel(const int* __restrict__ bfill,
                                                   const int* __restrict__ bucketBase,
                                                   const int2* __restrict__ tmp,
                                                   int* __restrict__ rowPtr,
                                                   int2* __restrict__ csr) {
    const int bucket = blockIdx.x;
    __shared__ int lhist[BROWS];
    __shared__ int rp[BROWS];
    __shared__ int fill[BROWS];
    const int t = threadIdx.x;
    lhist[t] = 0; fill[t] = 0;
    __syncthreads();

    const int cnt = bfill[bucket];
    const int2* src = tmp + (long)bucket * CAP;
    for (int k = t; k < cnt; k += 512)
        atomicAdd(&lhist[src[k].x >> 18], 1);
    __syncthreads();

    const int gb = bucketBase[bucket];
    if (t < 64) {
        int carry = 0;
        for (int cb = 0; cb < BROWS; cb += 64) {
            int i = cb + t;
            int orig = lhist[i];
            int x = orig;
            #pragma unroll
            for (int d = 1; d < 64; d <<= 1) {
                int tt = __shfl_up(x, d, 64);
                if (t >= d) x += tt;
            }
            int total = __shfl(x, 63, 64);
            rp[i] = x - orig + carry + gb;     // global exclusive offset
            carry += total;
        }
    }
    __syncthreads();

    int rowIdx = bucket * BROWS + t;           // max 150015; covers rowPtr[150000]
    rowPtr[rowIdx] = rp[t];

    for (int k = t; k < cnt; k += 512) {
        int2 p = src[k];
        int rL = p.x >> 18;
        int pos = rp[rL] + atomicAdd(&fill[rL], 1);
        csr[pos] = make_int2(p.x & 0x3FFFF, p.y);
    }
}

#define ACCX(V, X) { \
    a[0] += (V) * __uint_as_float((X).x << 16); \
    a[1] += (V) * __uint_as_float((X).x & 0xFFFF0000u); \
    a[2] += (V) * __uint_as_float((X).y << 16); \
    a[3] += (V) * __uint_as_float((X).y & 0xFFFF0000u); \
    a[4] += (V) * __uint_as_float((X).z << 16); \
    a[5] += (V) * __uint_as_float((X).z & 0xFFFF0000u); \
    a[6] += (V) * __uint_as_float((X).w << 16); \
    a[7] += (V) * __uint_as_float((X).w & 0xFFFF0000u); }

// --- SpMM: 8 lanes per row, each lane owns 8 bf16 dims (one uint4 gather) --
__global__ void spmm_csr(const int* __restrict__ rowPtr, const int2* __restrict__ csr,
                         const u16* __restrict__ cur, u16* __restrict__ nxt) {
    int gtid = blockIdx.x * blockDim.x + threadIdx.x;
    int row = gtid >> 3;
    int t   = gtid & 7;
    if (row >= NNODES) return;
    int beg = rowPtr[row], end = rowPtr[row + 1];
    float a[8];
    #pragma unroll
    for (int i = 0; i < 8; ++i) a[i] = 0.f;

    int e = beg;
    for (; e + 7 < end; e += 8) {            // 8 outstanding gathers
        int2 p[8];
        #pragma unroll
        for (int j = 0; j < 8; ++j) p[j] = csr[e + j];
        uint4 x[8];
        #pragma unroll
        for (int j = 0; j < 8; ++j)
            x[j] = *(const uint4*)(cur + ((long)p[j].x << 6) + (t << 3));
        #pragma unroll
        for (int j = 0; j < 8; ++j) {
            float v = __int_as_float(p[j].y);
            ACCX(v, x[j]);
        }
    }
    for (; e < end; ++e) {
        int2 p = csr[e];
        float v = __int_as_float(p.y);
        uint4 x = *(const uint4*)(cur + ((long)p.x << 6) + (t << 3));
        ACCX(v, x);
    }

    uint4 o;
    o.x = pack2(a[0], a[1]);
    o.y = pack2(a[2], a[3]);
    o.z = pack2(a[4], a[5]);
    o.w = pack2(a[6], a[7]);
    *(uint4*)(nxt + ((long)row << 6) + (t << 3)) = o;
}

// Layer 3 only at sampled rows: slot s<B -> users[s]; s<2B -> pos; s<3B -> neg.
// Output fp32 [NSAMP][64].
__global__ void spmm_sampled(const int* __restrict__ users,
                             const int* __restrict__ pos_items,
                             const int* __restrict__ neg_items,
                             const int* __restrict__ rowPtr, const int2* __restrict__ csr,
                             const u16* __restrict__ cur, float* __restrict__ sampled) {
    int gtid = blockIdx.x * blockDim.x + threadIdx.x;
    int slot = gtid >> 3;
    int t    = gtid & 7;
    if (slot >= NSAMP) return;
    int row;
    if (slot < BATCH)          row = users[slot];
    else if (slot < 2 * BATCH) row = pos_items[slot - BATCH] + NUM_USERS;
    else                       row = neg_items[slot - 2 * BATCH] + NUM_USERS;

    int beg = rowPtr[row], end = rowPtr[row + 1];
    float a[8];
    #pragma unroll
    for (int i = 0; i < 8; ++i) a[i] = 0.f;

    int e = beg;
    for (; e + 7 < end; e += 8) {
        int2 p[8];
        #pragma unroll
        for (int j = 0; j < 8; ++j) p[j] = csr[e + j];
        uint4 x[8];
        #pragma unroll
        for (int j = 0; j < 8; ++j)
            x[j] = *(const uint4*)(cur + ((long)p[j].x << 6) + (t << 3));
        #pragma unroll
        for (int j = 0; j < 8; ++j) {
            float v = __int_as_float(p[j].y);
            ACCX(v, x[j]);
        }
    }
    for (; e < end; ++e) {
        int2 p = csr[e];
        float v = __int_as_float(p.y);
        uint4 x = *(const uint4*)(cur + ((long)p.x << 6) + (t << 3));
        ACCX(v, x);
    }

    float4* dst = (float4*)(sampled + ((long)slot << 6) + (t << 3));
    dst[0] = make_float4(a[0], a[1], a[2], a[3]);
    dst[1] = make_float4(a[4], a[5], a[6], a[7]);
}

// One wave per batch element; lane = embedding dim.
// final = (emb + l1 + l2 + l3)/4 -> dot scaled by 1/16. l3 from sampled buf.
__global__ void score_kernel(const int* __restrict__ users,
                             const int* __restrict__ pos_items,
                             const int* __restrict__ neg_items,
                             const float* __restrict__ uemb,
                             const float* __restrict__ iemb,
                             const u16* __restrict__ l1,
                             const u16* __restrict__ l2,
                             const float* __restrict__ sampled,
                             float* __restrict__ out) {
    int gtid = blockIdx.x * blockDim.x + threadIdx.x;
    int wave = gtid >> 6;
    int lane = threadIdx.x & 63;
    if (wave >= BATCH) return;
    int u = users[wave];
    int p = pos_items[wave];
    int n = neg_items[wave];
    long U = (long)u * EMB + lane;
    long P = (long)(p + NUM_USERS) * EMB + lane;
    long N = (long)(n + NUM_USERS) * EMB + lane;
    float ue = uemb[(long)u * EMB + lane] + bf2f(l1[U]) + bf2f(l2[U])
             + sampled[(long)wave * EMB + lane];
    float pe = iemb[(long)p * EMB + lane] + bf2f(l1[P]) + bf2f(l2[P])
             + sampled[(long)(BATCH + wave) * EMB + lane];
    float ne = iemb[(long)n * EMB + lane] + bf2f(l1[N]) + bf2f(l2[N])
             + sampled[(long)(2 * BATCH + wave) * EMB + lane];
    float ps = ue * pe;
    float ns = ue * ne;
    #pragma unroll
    for (int off = 32; off > 0; off >>= 1) {
        ps += __shfl_down(ps, off, 64);
        ns += __shfl_down(ns, off, 64);
    }
    if (lane == 0) {
        out[wave]         = ps * 0.0625f;
        out[BATCH + wave] = ns * 0.0625f;
    }
}

extern "C" void kernel_launch(void* const* d_in, const int* in_sizes, int n_in,
                              void* d_out, int out_size, void* d_ws, size_t ws_size,
                              hipStream_t stream) {
    const int*   users = (const int*)d_in[0];
    const int*   pos   = (const int*)d_in[1];
    const int*   neg   = (const int*)d_in[2];
    const int*   rows  = (const int*)d_in[3];
    const int*   cols  = (const int*)d_in[4];
    const float* vals  = (const float*)d_in[5];
    const float* uemb  = (const float*)d_in[6];
    const float* iemb  = (const float*)d_in[7];
    float* out = (float*)d_out;

    const size_t tblElems = (size_t)NNODES * EMB;       // bf16 elems, 19.2 MB each
    u16*  B0      = (u16*)d_ws;                         // l0
    u16*  B1      = B0 + tblElems;                      // l1
    u16*  B2      = B1 + tblElems;                      // l2
    int2* csr     = (int2*)(B2 + tblElems);             // NEDGES int2 = 38.4 MB
    int*  rowPtr  = (int*)(csr + NEDGES);               // 150016 ints
    int*  bfill   = rowPtr + 150016;                    // pad 320
    int*  bucketB = bfill + 320;                        // pad 320
    float* sampled= (float*)(bucketB + 320);            // NSAMP*64 fp32 = 3.1 MB
    int*  tailEnd = (int*)(sampled + (size_t)NSAMP * EMB);

    const size_t tmpBytes = (size_t)BUCKETS * CAP * sizeof(int2);   // 40.8 MB
    const size_t baseBytes = (size_t)((char*)tailEnd - (char*)d_ws);
    const bool  bigws = ws_size >= baseBytes + tmpBytes;
    // bigws: tmp un-aliased -> init fused into binA's grid.
    // else : tmp aliases B0..B2 (consumed by binB before init writes B0).
    int2* tmp = bigws ? (int2*)tailEnd : (int2*)B0;

    hipMemsetAsync(bfill, 0, 320 * sizeof(int), stream);

    // CSR build: hist+reserve+scatter (+fused init) -> bucket scan -> resolve
    int gridA = NBLK_A + (bigws ? INIT_BLKS : 0);
    binA_kernel<<<gridA, 512, 0, stream>>>(rows, cols, vals, bfill, tmp,
                                           uemb, iemb, B0);
    scan_buckets<<<1, 64, 0, stream>>>(bfill, bucketB);
    binB_kernel<<<BUCKETS, 512, 0, stream>>>(bfill, bucketB, tmp, rowPtr, csr);

    if (!bigws) {
        const long n4 = (long)tblElems / 4;
        init_kernel<<<(int)((n4 + 255) / 256), 256, 0, stream>>>(uemb, iemb, B0);
    }

    // layers 1,2 full; layer 3 only at sampled rows
    const long nth = (long)NNODES * 8;
    const int  spmmGrid = (int)((nth + 255) / 256);
    spmm_csr<<<spmmGrid, 256, 0, stream>>>(rowPtr, csr, B0, B1);
    spmm_csr<<<spmmGrid, 256, 0, stream>>>(rowPtr, csr, B1, B2);
    spmm_sampled<<<(NSAMP * 8 + 255) / 256, 256, 0, stream>>>(users, pos, neg,
                                                              rowPtr, csr, B2, sampled);

    score_kernel<<<(BATCH * 64) / 256, 256, 0, stream>>>(users, pos, neg,
                                                         uemb, iemb, B1, B2, sampled, out);
}